// Round 1
// baseline (251.118 us; speedup 1.0000x reference)
//
#include <hip/hip_runtime.h>

// SSIM (window=8 box sums) over 96 images of 512x512 fp32.
// v7 = v6 restructured for occupancy + load flight:
//  - LDS 4 row-slots -> 2 row-slots (33.3 KB -> 16.6 KB): blocks/CU 4 -> 8-9,
//    waves/CU 8 -> 16-18.  Occupancy was the binding constraint (VALUBusy 27%,
//    2 waves/SIMD, per-wave duty ~13%).
//  - __syncthreads() -> raw s_barrier + explicit s_waitcnt lgkmcnt(0): hipcc's
//    __syncthreads drains vmcnt(0), killing prefetch flight at every barrier.
//    LDS producer->consumer only needs lgkmcnt.  Prefetched global loads now
//    stay in flight across the barrier into the next group's phase A.
//  - groups of 2 rows (was 4): phase A (2 rows vertical + publish LDS), bar,
//    issue 4 prefetch loads, phase B (2 rows HORIZ+SSIM), bar.
//  - __launch_bounds__(128,4): VGPR cap 128 (persistent ~110: ring 64 +
//    vsums 16 + pf 16 + addr).  Watch VGPR_Count/scratch next round.
// All DS layout/indexing identical to v6 (16 B lane stride, measured clean).

#define W 512
#define H 512
#define OW 505
#define OH 505
#define TH 16
#define NSTRIP ((OH + TH - 1) / TH)   // 32
#define NIMG 96
#define NPIX (96.0 * 505.0 * 505.0)   // 24482400

__device__ __forceinline__ float4 ld4(const float* p) { return *(const float4*)p; }
__device__ __forceinline__ float4 f4add(float4 a, float4 b) {
    return make_float4(a.x + b.x, a.y + b.y, a.z + b.z, a.w + b.w);
}
__device__ __forceinline__ float4 f4sub(float4 a, float4 b) {
    return make_float4(a.x - b.x, a.y - b.y, a.z - b.z, a.w - b.w);
}
__device__ __forceinline__ float4 f4mul(float4 a, float4 b) {
    return make_float4(a.x * b.x, a.y * b.y, a.z * b.z, a.w * b.w);
}

// LDS-only barrier: order this wave's ds ops, then sync the block.
// Deliberately NOT __syncthreads(): that drains vmcnt(0) and would kill the
// global prefetch loads' flight across the barrier.
__device__ __forceinline__ void wbar() {
    asm volatile("s_waitcnt lgkmcnt(0)" ::: "memory");
    __builtin_amdgcn_s_barrier();
}

__global__ void finalize(const double* p, float* out) {
    out[0] = 1.0f - (float)(*p / NPIX);
}

__global__ void __launch_bounds__(128, 4)
ssim_main(const float* __restrict__ gt, const float* __restrict__ ni,
          double* __restrict__ acc_out)
{
    const int t   = threadIdx.x;      // 0..127
    const int c0  = t * 4;            // base column (0..508)
    const int img = blockIdx.y;
    const int R0  = blockIdx.x * TH;  // first output row of strip (mult of 8)
    const int R1  = min(R0 + TH, OH);

    const float C1 = 1e-4f;
    const float C2 = 9e-4f;

    const float* gx = gt + (size_t)img * (W * H) + c0;
    const float* gy = ni + (size_t)img * (W * H) + c0;

    // 2 row-slots x 4 quantities x 520 cols (width 520: threads 126/127 read
    // past col 511 -> garbage, predicated out of the accumulate).
    __shared__ float vbuf[2][4][520];
    __shared__ float wpart[2];

    float4 ring_x[8], ring_y[8];
    float4 vsx = make_float4(0, 0, 0, 0);   // sum x
    float4 vsy = make_float4(0, 0, 0, 0);   // sum y
    float4 vsq = make_float4(0, 0, 0, 0);   // sum x^2 + y^2
    float4 vsp = make_float4(0, 0, 0, 0);   // sum x*y

    // warm-up: rows R0..R0+6 -> ring slots 0..6; slot 7 = zeros
#pragma unroll
    for (int k = 0; k < 7; ++k) {
        float4 x = ld4(gx + (size_t)(R0 + k) * W);
        float4 y = ld4(gy + (size_t)(R0 + k) * W);
        ring_x[k] = x; ring_y[k] = y;
        vsx = f4add(vsx, x);
        vsy = f4add(vsy, y);
        vsq = f4add(vsq, f4add(f4mul(x, x), f4mul(y, y)));
        vsp = f4add(vsp, f4mul(x, y));
    }
    ring_x[7] = make_float4(0, 0, 0, 0);
    ring_y[7] = make_float4(0, 0, 0, 0);

    // prefetch rows R0+7, R0+8 (R0 <= 496 -> rows <= 504 < 512, always valid)
    float4 pfx[2], pfy[2];
    pfx[0] = ld4(gx + (size_t)(R0 + 7) * W);
    pfy[0] = ld4(gy + (size_t)(R0 + 7) * W);
    pfx[1] = ld4(gx + (size_t)(R0 + 8) * W);
    pfy[1] = ld4(gy + (size_t)(R0 + 8) * W);

    float acc = 0.0f;

// phase A, one row: consume prefetch slot m, slide vsums, publish LDS row m
#define PHASEA_ROW(rb, m, slot) {                                         \
        if ((rb) + (m) < R1) { /* block-uniform */                        \
            float4 cx = pfx[m], cy = pfy[m];                              \
            float4 ox = ring_x[slot], oy = ring_y[slot];                  \
            vsx = f4add(f4sub(vsx, ox), cx);                              \
            vsy = f4add(f4sub(vsy, oy), cy);                              \
            vsq = f4add(vsq, f4sub(f4add(f4mul(cx, cx), f4mul(cy, cy)),   \
                                   f4add(f4mul(ox, ox), f4mul(oy, oy)))); \
            vsp = f4add(vsp, f4sub(f4mul(cx, cy), f4mul(ox, oy)));        \
            ring_x[slot] = cx; ring_y[slot] = cy;                         \
            *(float4*)&vbuf[m][0][c0] = vsx;                              \
            *(float4*)&vbuf[m][1][c0] = vsy;                              \
            *(float4*)&vbuf[m][2][c0] = vsq;                              \
            *(float4*)&vbuf[m][3][c0] = vsp;                              \
        }                                                                 \
    }

// 8-wide horizontal sliding sums from 3 LDS float4s (own, +4, +8)
#define HORIZ(q) {                                                        \
        float4 o = *(float4*)&vbuf[m][q][c0];                             \
        float4 a = *(float4*)&vbuf[m][q][c0 + 4];                         \
        float4 e = *(float4*)&vbuf[m][q][c0 + 8];                         \
        float s = ((o.x + o.y) + (o.z + o.w)) +                           \
                  ((a.x + a.y) + (a.z + a.w));                            \
        B[q][0] = s;                                                      \
        s += e.x - o.x; B[q][1] = s;                                      \
        s += e.y - o.y; B[q][2] = s;                                      \
        s += e.z - o.z; B[q][3] = s;                                      \
    }

// phase B, one row: horizontal sums + SSIM + accumulate
#define PHASEB_ROW(rb, mm) {                                              \
        if ((rb) + (mm) < R1) { /* block-uniform */                       \
            const int m = (mm);                                           \
            float B[4][4];                                                \
            HORIZ(0) HORIZ(1) HORIZ(2) HORIZ(3)                           \
            _Pragma("unroll")                                             \
            for (int j = 0; j < 4; ++j) {                                 \
                float Sx = B[0][j], Sy = B[1][j];                         \
                float Sq = B[2][j], Sp = B[3][j];                         \
                float mu12 = Sx * Sy;                                     \
                float n1v = 2.0f * mu12 + C1;                             \
                float n2v = 2.0f * (Sp - mu12) + C2;                      \
                float sx2 = Sx * Sx, sy2 = Sy * Sy;                       \
                float d1  = sx2 + sy2 + C1;                               \
                float d2  = (Sq - sx2 - sy2) + C2;                        \
                float sv  = (n1v * n2v) * __builtin_amdgcn_rcpf(d1 * d2); \
                if (c0 + j < OW) acc += sv;                               \
            }                                                             \
        }                                                                 \
    }

// one group = 2 rows: phase A, bar, prefetch-issue, phase B, bar.
// prefetch rows (rb)+9,(rb)+10 are consumed as pfx[0],pfx[1] by group rb+2;
// guards (rb)+2+m < R1 match the consumer's (rb+2)+m < R1 exactly.
// max row read: (rb)+10 with (rb)+3 < R1 <= 505 -> row <= 511, in bounds.
#define GROUP2(rb, s0, s1) {                                              \
        if ((rb) < R1) { /* block-uniform */                              \
            PHASEA_ROW(rb, 0, s0) PHASEA_ROW(rb, 1, s1)                   \
            wbar();                                                       \
            if ((rb) + 2 < R1) {                                          \
                pfx[0] = ld4(gx + (size_t)((rb) + 9) * W);                \
                pfy[0] = ld4(gy + (size_t)((rb) + 9) * W);                \
            }                                                             \
            if ((rb) + 3 < R1) {                                          \
                pfx[1] = ld4(gx + (size_t)((rb) + 10) * W);               \
                pfy[1] = ld4(gy + (size_t)((rb) + 10) * W);               \
            }                                                             \
            PHASEB_ROW(rb, 0) PHASEB_ROW(rb, 1)                           \
            wbar();                                                       \
        }                                                                 \
    }

    // R0 mult of 8 -> ring slot for output row r is ((r-R0)+7)&7:
    // groups cycle slots (7,0),(1,2),(3,4),(5,6) per 8 rows.
    for (int rb0 = R0; rb0 < R1; rb0 += 8) {
        GROUP2(rb0,     7, 0)
        GROUP2(rb0 + 2, 1, 2)
        GROUP2(rb0 + 4, 3, 4)
        GROUP2(rb0 + 6, 5, 6)
    }

    // reduction: wave shuffle -> LDS -> one double atomic per block
#pragma unroll
    for (int off = 32; off > 0; off >>= 1) acc += __shfl_down(acc, off);
    const int wave = t >> 6, lane = t & 63;
    if (lane == 0) wpart[wave] = acc;
    __syncthreads();
    if (t == 0) atomicAdd(acc_out, (double)(wpart[0] + wpart[1]));
}

extern "C" void kernel_launch(void* const* d_in, const int* in_sizes, int n_in,
                              void* d_out, int out_size, void* d_ws, size_t ws_size,
                              hipStream_t stream) {
    const float* gt = (const float*)d_in[0];
    const float* ni = (const float*)d_in[1];
    double* acc = (double*)d_ws;   // 8 bytes scratch, re-poisoned every call

    hipMemsetAsync(acc, 0, sizeof(double), stream);
    dim3 grid(NSTRIP, NIMG);
    ssim_main<<<grid, 128, 0, stream>>>(gt, ni, acc);
    finalize<<<1, 1, 0, stream>>>(acc, (float*)d_out);
}

// Round 2
// 233.508 us; speedup vs baseline: 1.0754x; 1.0754x over previous
//
#include <hip/hip_runtime.h>

// SSIM (window=8 box sums) over 96 images of 512x512 fp32.
// v8 = v7 with the spill fixed:
//  - v7's __launch_bounds__(128,4) capped VGPR at 128 -> allocator collapsed
//    to 64 VGPR and spilled the ring to scratch (WRITE_SIZE 96 KB -> 76 MB,
//    dur 97 -> 112 us).  Revert to (128,2) (cap 256; v6 compiled 88 VGPR,
//    no spill).  Residency is then LDS-limited at 9 blocks/CU (16.9 KB),
//    ~4.5 waves/SIMD -- the occupancy v7 was after, without the spill tax.
//  - keep v7's 2-row-slot LDS (16.6 KB) and lgkmcnt-only barriers (prefetch
//    loads stay in flight across barriers; v7 confirmed occupancy 17->34%
//    and HBM 1.5->2.2 TB/s from these).

#define W 512
#define H 512
#define OW 505
#define OH 505
#define TH 16
#define NSTRIP ((OH + TH - 1) / TH)   // 32
#define NIMG 96
#define NPIX (96.0 * 505.0 * 505.0)   // 24482400

__device__ __forceinline__ float4 ld4(const float* p) { return *(const float4*)p; }
__device__ __forceinline__ float4 f4add(float4 a, float4 b) {
    return make_float4(a.x + b.x, a.y + b.y, a.z + b.z, a.w + b.w);
}
__device__ __forceinline__ float4 f4sub(float4 a, float4 b) {
    return make_float4(a.x - b.x, a.y - b.y, a.z - b.z, a.w - b.w);
}
__device__ __forceinline__ float4 f4mul(float4 a, float4 b) {
    return make_float4(a.x * b.x, a.y * b.y, a.z * b.z, a.w * b.w);
}

// LDS-only barrier: order this wave's ds ops, then sync the block.
// Deliberately NOT __syncthreads(): that drains vmcnt(0) and would kill the
// global prefetch loads' flight across the barrier.
__device__ __forceinline__ void wbar() {
    asm volatile("s_waitcnt lgkmcnt(0)" ::: "memory");
    __builtin_amdgcn_s_barrier();
}

__global__ void finalize(const double* p, float* out) {
    out[0] = 1.0f - (float)(*p / NPIX);
}

__global__ void __launch_bounds__(128, 2)
ssim_main(const float* __restrict__ gt, const float* __restrict__ ni,
          double* __restrict__ acc_out)
{
    const int t   = threadIdx.x;      // 0..127
    const int c0  = t * 4;            // base column (0..508)
    const int img = blockIdx.y;
    const int R0  = blockIdx.x * TH;  // first output row of strip (mult of 8)
    const int R1  = min(R0 + TH, OH);

    const float C1 = 1e-4f;
    const float C2 = 9e-4f;

    const float* gx = gt + (size_t)img * (W * H) + c0;
    const float* gy = ni + (size_t)img * (W * H) + c0;

    // 2 row-slots x 4 quantities x 520 cols (width 520: threads 126/127 read
    // past col 511 -> garbage, predicated out of the accumulate).
    __shared__ float vbuf[2][4][520];
    __shared__ float wpart[2];

    float4 ring_x[8], ring_y[8];
    float4 vsx = make_float4(0, 0, 0, 0);   // sum x
    float4 vsy = make_float4(0, 0, 0, 0);   // sum y
    float4 vsq = make_float4(0, 0, 0, 0);   // sum x^2 + y^2
    float4 vsp = make_float4(0, 0, 0, 0);   // sum x*y

    // warm-up: rows R0..R0+6 -> ring slots 0..6; slot 7 = zeros
#pragma unroll
    for (int k = 0; k < 7; ++k) {
        float4 x = ld4(gx + (size_t)(R0 + k) * W);
        float4 y = ld4(gy + (size_t)(R0 + k) * W);
        ring_x[k] = x; ring_y[k] = y;
        vsx = f4add(vsx, x);
        vsy = f4add(vsy, y);
        vsq = f4add(vsq, f4add(f4mul(x, x), f4mul(y, y)));
        vsp = f4add(vsp, f4mul(x, y));
    }
    ring_x[7] = make_float4(0, 0, 0, 0);
    ring_y[7] = make_float4(0, 0, 0, 0);

    // prefetch rows R0+7, R0+8 (R0 <= 496 -> rows <= 504 < 512, always valid)
    float4 pfx[2], pfy[2];
    pfx[0] = ld4(gx + (size_t)(R0 + 7) * W);
    pfy[0] = ld4(gy + (size_t)(R0 + 7) * W);
    pfx[1] = ld4(gx + (size_t)(R0 + 8) * W);
    pfy[1] = ld4(gy + (size_t)(R0 + 8) * W);

    float acc = 0.0f;

// phase A, one row: consume prefetch slot m, slide vsums, publish LDS row m
#define PHASEA_ROW(rb, m, slot) {                                         \
        if ((rb) + (m) < R1) { /* block-uniform */                        \
            float4 cx = pfx[m], cy = pfy[m];                              \
            float4 ox = ring_x[slot], oy = ring_y[slot];                  \
            vsx = f4add(f4sub(vsx, ox), cx);                              \
            vsy = f4add(f4sub(vsy, oy), cy);                              \
            vsq = f4add(vsq, f4sub(f4add(f4mul(cx, cx), f4mul(cy, cy)),   \
                                   f4add(f4mul(ox, ox), f4mul(oy, oy)))); \
            vsp = f4add(vsp, f4sub(f4mul(cx, cy), f4mul(ox, oy)));        \
            ring_x[slot] = cx; ring_y[slot] = cy;                         \
            *(float4*)&vbuf[m][0][c0] = vsx;                              \
            *(float4*)&vbuf[m][1][c0] = vsy;                              \
            *(float4*)&vbuf[m][2][c0] = vsq;                              \
            *(float4*)&vbuf[m][3][c0] = vsp;                              \
        }                                                                 \
    }

// 8-wide horizontal sliding sums from 3 LDS float4s (own, +4, +8)
#define HORIZ(q) {                                                        \
        float4 o = *(float4*)&vbuf[m][q][c0];                             \
        float4 a = *(float4*)&vbuf[m][q][c0 + 4];                         \
        float4 e = *(float4*)&vbuf[m][q][c0 + 8];                         \
        float s = ((o.x + o.y) + (o.z + o.w)) +                           \
                  ((a.x + a.y) + (a.z + a.w));                            \
        B[q][0] = s;                                                      \
        s += e.x - o.x; B[q][1] = s;                                      \
        s += e.y - o.y; B[q][2] = s;                                      \
        s += e.z - o.z; B[q][3] = s;                                      \
    }

// phase B, one row: horizontal sums + SSIM + accumulate
#define PHASEB_ROW(rb, mm) {                                              \
        if ((rb) + (mm) < R1) { /* block-uniform */                       \
            const int m = (mm);                                           \
            float B[4][4];                                                \
            HORIZ(0) HORIZ(1) HORIZ(2) HORIZ(3)                           \
            _Pragma("unroll")                                             \
            for (int j = 0; j < 4; ++j) {                                 \
                float Sx = B[0][j], Sy = B[1][j];                         \
                float Sq = B[2][j], Sp = B[3][j];                         \
                float mu12 = Sx * Sy;                                     \
                float n1v = 2.0f * mu12 + C1;                             \
                float n2v = 2.0f * (Sp - mu12) + C2;                      \
                float sx2 = Sx * Sx, sy2 = Sy * Sy;                       \
                float d1  = sx2 + sy2 + C1;                               \
                float d2  = (Sq - sx2 - sy2) + C2;                        \
                float sv  = (n1v * n2v) * __builtin_amdgcn_rcpf(d1 * d2); \
                if (c0 + j < OW) acc += sv;                               \
            }                                                             \
        }                                                                 \
    }

// one group = 2 rows: phase A, bar, prefetch-issue, phase B, bar.
// prefetch rows (rb)+9,(rb)+10 are consumed as pfx[0],pfx[1] by group rb+2;
// guards (rb)+2+m < R1 match the consumer's (rb+2)+m < R1 exactly.
// max row read: (rb)+10 with (rb)+3 < R1 <= 505 -> row <= 511, in bounds.
#define GROUP2(rb, s0, s1) {                                              \
        if ((rb) < R1) { /* block-uniform */                              \
            PHASEA_ROW(rb, 0, s0) PHASEA_ROW(rb, 1, s1)                   \
            wbar();                                                       \
            if ((rb) + 2 < R1) {                                          \
                pfx[0] = ld4(gx + (size_t)((rb) + 9) * W);                \
                pfy[0] = ld4(gy + (size_t)((rb) + 9) * W);                \
            }                                                             \
            if ((rb) + 3 < R1) {                                          \
                pfx[1] = ld4(gx + (size_t)((rb) + 10) * W);               \
                pfy[1] = ld4(gy + (size_t)((rb) + 10) * W);               \
            }                                                             \
            PHASEB_ROW(rb, 0) PHASEB_ROW(rb, 1)                           \
            wbar();                                                       \
        }                                                                 \
    }

    // R0 mult of 8 -> ring slot for output row r is ((r-R0)+7)&7:
    // groups cycle slots (7,0),(1,2),(3,4),(5,6) per 8 rows.
    for (int rb0 = R0; rb0 < R1; rb0 += 8) {
        GROUP2(rb0,     7, 0)
        GROUP2(rb0 + 2, 1, 2)
        GROUP2(rb0 + 4, 3, 4)
        GROUP2(rb0 + 6, 5, 6)
    }

    // reduction: wave shuffle -> LDS -> one double atomic per block
#pragma unroll
    for (int off = 32; off > 0; off >>= 1) acc += __shfl_down(acc, off);
    const int wave = t >> 6, lane = t & 63;
    if (lane == 0) wpart[wave] = acc;
    __syncthreads();
    if (t == 0) atomicAdd(acc_out, (double)(wpart[0] + wpart[1]));
}

extern "C" void kernel_launch(void* const* d_in, const int* in_sizes, int n_in,
                              void* d_out, int out_size, void* d_ws, size_t ws_size,
                              hipStream_t stream) {
    const float* gt = (const float*)d_in[0];
    const float* ni = (const float*)d_in[1];
    double* acc = (double*)d_ws;   // 8 bytes scratch, re-poisoned every call

    hipMemsetAsync(acc, 0, sizeof(double), stream);
    dim3 grid(NSTRIP, NIMG);
    ssim_main<<<grid, 128, 0, stream>>>(gt, ni, acc);
    finalize<<<1, 1, 0, stream>>>(acc, (float*)d_out);
}